// Round 1
// baseline (843.648 us; speedup 1.0000x reference)
//
#include <hip/hip_runtime.h>

#define H 1024
#define DFF 2048
#define NE 8
#define NT 2048            // B*S tokens
#define NPAIR (NT * 2)     // TOPK=2
#define BM 64
#define BN 64
#define BK 32
#define LDK 40             // padded k-stride (shorts): 80B rows, 16B-aligned, 2-way bank alias (free)

typedef __bf16 bf16;
typedef __bf16 bf16x8 __attribute__((ext_vector_type(8)));
typedef float f32x4 __attribute__((ext_vector_type(4)));

// ---------------- gate: logits -> top2 -> softmax ----------------
__global__ __launch_bounds__(64) void gate_kernel(
    const float* __restrict__ x, const float* __restrict__ gw,
    const float* __restrict__ gb, int* __restrict__ cnt,
    int* __restrict__ topi, float* __restrict__ topw) {
  int t = blockIdx.x;
  int lane = threadIdx.x;
  const float* xr = x + (size_t)t * H;
  float acc[NE];
#pragma unroll
  for (int e = 0; e < NE; ++e) acc[e] = 0.f;
  for (int i = lane; i < H; i += 64) {
    float xv = xr[i];
    const float* g = gw + (size_t)i * NE;
#pragma unroll
    for (int e = 0; e < NE; ++e) acc[e] += xv * g[e];
  }
#pragma unroll
  for (int e = 0; e < NE; ++e) {
    for (int off = 32; off > 0; off >>= 1)
      acc[e] += __shfl_down(acc[e], off, 64);
  }
  if (lane == 0) {
    float v[NE];
#pragma unroll
    for (int e = 0; e < NE; ++e) v[e] = acc[e] + gb[e];
    int i1 = 0;
#pragma unroll
    for (int e = 1; e < NE; ++e) if (v[e] > v[i1]) i1 = e;     // lowest index on ties (jax top_k)
    int i2 = (i1 == 0) ? 1 : 0;
#pragma unroll
    for (int e = 0; e < NE; ++e) if (e != i1 && v[e] > v[i2]) i2 = e;
    float d = expf(v[i2] - v[i1]);       // <= 1
    float p1 = 1.f / (1.f + d);
    float p2 = d * p1;
    topi[2 * t] = i1; topi[2 * t + 1] = i2;
    topw[2 * t] = p1; topw[2 * t + 1] = p2;
    atomicAdd(&cnt[i1], 1);
    atomicAdd(&cnt[i2], 1);
  }
}

__global__ void prefix_kernel(const int* __restrict__ cnt, int* __restrict__ off) {
  if (threadIdx.x == 0 && blockIdx.x == 0) {
    int s = 0;
    for (int e = 0; e < NE; ++e) { off[e] = s; s += cnt[e]; }
    off[NE] = s;
  }
}

__global__ __launch_bounds__(256) void scatter_kernel(
    const int* __restrict__ topi, int* __restrict__ cnt2,
    const int* __restrict__ off, int* __restrict__ pair_tok,
    int* __restrict__ pair_pos) {
  int t = blockIdx.x * 256 + threadIdx.x;
  if (t >= NT) return;
#pragma unroll
  for (int k = 0; k < 2; ++k) {
    int e = topi[2 * t + k];
    int idx = atomicAdd(&cnt2[e], 1);
    int pos = off[e] + idx;
    pair_tok[pos] = t;
    pair_pos[2 * t + k] = pos;
  }
}

// ---------------- stage 1: z = (x@w1+b1)*(x@w2+b2), gathered per expert ----------------
__global__ __launch_bounds__(256) void ffn1_kernel(
    const float* __restrict__ x, const float* __restrict__ w1,
    const float* __restrict__ b1, const float* __restrict__ w2,
    const float* __restrict__ b2, const int* __restrict__ off,
    const int* __restrict__ pair_tok, bf16* __restrict__ Z) {
  int e = blockIdx.y;
  int base = off[e];
  int count = off[e + 1] - base;
  int m0 = blockIdx.z * BM;
  if (m0 >= count) return;
  int n0 = blockIdx.x * BN;

  __shared__ bf16 As[BM][LDK];
  __shared__ bf16 B1s[BN][LDK];
  __shared__ bf16 B2s[BN][LDK];
  __shared__ int toks[BM];

  int tid = threadIdx.x;
  if (tid < BM) {
    int m = m0 + tid;
    if (m >= count) m = count - 1;
    toks[tid] = pair_tok[base + m];
  }
  __syncthreads();

  const float* W1e = w1 + (size_t)e * H * DFF;
  const float* W2e = w2 + (size_t)e * H * DFF;

  f32x4 zero = {0.f, 0.f, 0.f, 0.f};
  f32x4 acc1[4], acc2[4];
#pragma unroll
  for (int c = 0; c < 4; ++c) { acc1[c] = zero; acc2[c] = zero; }

  int wave = tid >> 6, lane = tid & 63;
  int quad = lane >> 4, l16 = lane & 15;
  int am = tid >> 2, ak = (tid & 3) * 8;     // A staging: token row, k chunk
  int bk = tid >> 3, bn = (tid & 7) * 8;     // B staging: k row, n chunk

  for (int k0 = 0; k0 < H; k0 += BK) {
    const float* asrc = x + (size_t)toks[am] * H + k0 + ak;
    float4 a0 = *(const float4*)asrc;
    float4 a1 = *(const float4*)(asrc + 4);
    bf16* ad = &As[am][ak];
    ad[0] = (bf16)a0.x; ad[1] = (bf16)a0.y; ad[2] = (bf16)a0.z; ad[3] = (bf16)a0.w;
    ad[4] = (bf16)a1.x; ad[5] = (bf16)a1.y; ad[6] = (bf16)a1.z; ad[7] = (bf16)a1.w;

    const float* s1 = W1e + (size_t)(k0 + bk) * DFF + n0 + bn;
    float4 c0 = *(const float4*)s1;
    float4 c1 = *(const float4*)(s1 + 4);
    B1s[bn + 0][bk] = (bf16)c0.x; B1s[bn + 1][bk] = (bf16)c0.y;
    B1s[bn + 2][bk] = (bf16)c0.z; B1s[bn + 3][bk] = (bf16)c0.w;
    B1s[bn + 4][bk] = (bf16)c1.x; B1s[bn + 5][bk] = (bf16)c1.y;
    B1s[bn + 6][bk] = (bf16)c1.z; B1s[bn + 7][bk] = (bf16)c1.w;

    const float* s2 = W2e + (size_t)(k0 + bk) * DFF + n0 + bn;
    float4 d0 = *(const float4*)s2;
    float4 d1 = *(const float4*)(s2 + 4);
    B2s[bn + 0][bk] = (bf16)d0.x; B2s[bn + 1][bk] = (bf16)d0.y;
    B2s[bn + 2][bk] = (bf16)d0.z; B2s[bn + 3][bk] = (bf16)d0.w;
    B2s[bn + 4][bk] = (bf16)d1.x; B2s[bn + 5][bk] = (bf16)d1.y;
    B2s[bn + 6][bk] = (bf16)d1.z; B2s[bn + 7][bk] = (bf16)d1.w;

    __syncthreads();

    bf16x8 af = *(const bf16x8*)&As[wave * 16 + l16][quad * 8];
#pragma unroll
    for (int c = 0; c < 4; ++c) {
      bf16x8 bf1 = *(const bf16x8*)&B1s[c * 16 + l16][quad * 8];
      acc1[c] = __builtin_amdgcn_mfma_f32_16x16x32_bf16(af, bf1, acc1[c], 0, 0, 0);
    }
#pragma unroll
    for (int c = 0; c < 4; ++c) {
      bf16x8 bf2 = *(const bf16x8*)&B2s[c * 16 + l16][quad * 8];
      acc2[c] = __builtin_amdgcn_mfma_f32_16x16x32_bf16(af, bf2, acc2[c], 0, 0, 0);
    }
    __syncthreads();
  }

  int mbase = m0 + wave * 16 + quad * 4;
#pragma unroll
  for (int c = 0; c < 4; ++c) {
    int n = n0 + c * 16 + l16;
    float bb1 = b1[e * DFF + n];
    float bb2 = b2[e * DFF + n];
#pragma unroll
    for (int r = 0; r < 4; ++r) {
      int m = mbase + r;
      if (m < count) {
        float zv = (acc1[c][r] + bb1) * (acc2[c][r] + bb2);
        Z[(size_t)(base + m) * DFF + n] = (bf16)zv;
      }
    }
  }
}

// ---------------- stage 2: s = silu(z@wg + bg) ----------------
__global__ __launch_bounds__(256) void ffn2_kernel(
    const bf16* __restrict__ Z, const float* __restrict__ wg,
    const float* __restrict__ bg, const int* __restrict__ off,
    bf16* __restrict__ S) {
  int e = blockIdx.y;
  int base = off[e];
  int count = off[e + 1] - base;
  int m0 = blockIdx.z * BM;
  if (m0 >= count) return;
  int n0 = blockIdx.x * BN;

  __shared__ bf16 As[BM][LDK];
  __shared__ bf16 Bs[BN][LDK];

  int tid = threadIdx.x;
  int wave = tid >> 6, lane = tid & 63;
  int quad = lane >> 4, l16 = lane & 15;
  int am = tid >> 2, ak = (tid & 3) * 8;
  int bk = tid >> 3, bn = (tid & 7) * 8;

  int amr = m0 + am; if (amr >= count) amr = count - 1;
  const bf16* asrc = Z + (size_t)(base + amr) * DFF + ak;
  const float* We = wg + (size_t)e * DFF * DFF;

  f32x4 zero = {0.f, 0.f, 0.f, 0.f};
  f32x4 acc[4];
#pragma unroll
  for (int c = 0; c < 4; ++c) acc[c] = zero;

  for (int k0 = 0; k0 < DFF; k0 += BK) {
    *(bf16x8*)&As[am][ak] = *(const bf16x8*)(asrc + k0);

    const float* s1 = We + (size_t)(k0 + bk) * DFF + n0 + bn;
    float4 c0 = *(const float4*)s1;
    float4 c1 = *(const float4*)(s1 + 4);
    Bs[bn + 0][bk] = (bf16)c0.x; Bs[bn + 1][bk] = (bf16)c0.y;
    Bs[bn + 2][bk] = (bf16)c0.z; Bs[bn + 3][bk] = (bf16)c0.w;
    Bs[bn + 4][bk] = (bf16)c1.x; Bs[bn + 5][bk] = (bf16)c1.y;
    Bs[bn + 6][bk] = (bf16)c1.z; Bs[bn + 7][bk] = (bf16)c1.w;

    __syncthreads();

    bf16x8 af = *(const bf16x8*)&As[wave * 16 + l16][quad * 8];
#pragma unroll
    for (int c = 0; c < 4; ++c) {
      bf16x8 bfv = *(const bf16x8*)&Bs[c * 16 + l16][quad * 8];
      acc[c] = __builtin_amdgcn_mfma_f32_16x16x32_bf16(af, bfv, acc[c], 0, 0, 0);
    }
    __syncthreads();
  }

  int mbase = m0 + wave * 16 + quad * 4;
#pragma unroll
  for (int c = 0; c < 4; ++c) {
    int n = n0 + c * 16 + l16;
    float bb = bg[e * DFF + n];
#pragma unroll
    for (int r = 0; r < 4; ++r) {
      int m = mbase + r;
      if (m < count) {
        float v = acc[c][r] + bb;
        float s = v / (1.f + expf(-v));
        S[(size_t)(base + m) * DFF + n] = (bf16)s;
      }
    }
  }
}

// ---------------- stage 3: y = s@w3 + b3 (per pair) ----------------
__global__ __launch_bounds__(256) void ffn3_kernel(
    const bf16* __restrict__ S, const float* __restrict__ w3,
    const float* __restrict__ b3, const int* __restrict__ off,
    float* __restrict__ Y) {
  int e = blockIdx.y;
  int base = off[e];
  int count = off[e + 1] - base;
  int m0 = blockIdx.z * BM;
  if (m0 >= count) return;
  int n0 = blockIdx.x * BN;

  __shared__ bf16 As[BM][LDK];
  __shared__ bf16 Bs[BN][LDK];

  int tid = threadIdx.x;
  int wave = tid >> 6, lane = tid & 63;
  int quad = lane >> 4, l16 = lane & 15;
  int am = tid >> 2, ak = (tid & 3) * 8;
  int bk = tid >> 3, bn = (tid & 7) * 8;

  int amr = m0 + am; if (amr >= count) amr = count - 1;
  const bf16* asrc = S + (size_t)(base + amr) * DFF + ak;
  const float* We = w3 + (size_t)e * DFF * H;

  f32x4 zero = {0.f, 0.f, 0.f, 0.f};
  f32x4 acc[4];
#pragma unroll
  for (int c = 0; c < 4; ++c) acc[c] = zero;

  for (int k0 = 0; k0 < DFF; k0 += BK) {
    *(bf16x8*)&As[am][ak] = *(const bf16x8*)(asrc + k0);

    const float* s1 = We + (size_t)(k0 + bk) * H + n0 + bn;
    float4 c0 = *(const float4*)s1;
    float4 c1 = *(const float4*)(s1 + 4);
    Bs[bn + 0][bk] = (bf16)c0.x; Bs[bn + 1][bk] = (bf16)c0.y;
    Bs[bn + 2][bk] = (bf16)c0.z; Bs[bn + 3][bk] = (bf16)c0.w;
    Bs[bn + 4][bk] = (bf16)c1.x; Bs[bn + 5][bk] = (bf16)c1.y;
    Bs[bn + 6][bk] = (bf16)c1.z; Bs[bn + 7][bk] = (bf16)c1.w;

    __syncthreads();

    bf16x8 af = *(const bf16x8*)&As[wave * 16 + l16][quad * 8];
#pragma unroll
    for (int c = 0; c < 4; ++c) {
      bf16x8 bfv = *(const bf16x8*)&Bs[c * 16 + l16][quad * 8];
      acc[c] = __builtin_amdgcn_mfma_f32_16x16x32_bf16(af, bfv, acc[c], 0, 0, 0);
    }
    __syncthreads();
  }

  int mbase = m0 + wave * 16 + quad * 4;
#pragma unroll
  for (int c = 0; c < 4; ++c) {
    int n = n0 + c * 16 + l16;
    float bb = b3[e * H + n];
#pragma unroll
    for (int r = 0; r < 4; ++r) {
      int m = mbase + r;
      if (m < count) {
        Y[(size_t)(base + m) * H + n] = acc[c][r] + bb;
      }
    }
  }
}

// ---------------- combine: out[t] = w0*Y[p0] + w1*Y[p1] ----------------
__global__ __launch_bounds__(256) void combine_kernel(
    const float* __restrict__ Y, const int* __restrict__ pair_pos,
    const float* __restrict__ topw, float* __restrict__ out) {
  int idx = blockIdx.x * 256 + threadIdx.x;   // one float4 per thread
  int t = idx >> 8;                           // H/4 = 256 float4 per token
  int h4 = idx & 255;
  int p0 = pair_pos[2 * t], p1 = pair_pos[2 * t + 1];
  float w0 = topw[2 * t], w1 = topw[2 * t + 1];
  float4 a = ((const float4*)(Y + (size_t)p0 * H))[h4];
  float4 b = ((const float4*)(Y + (size_t)p1 * H))[h4];
  float4 o;
  o.x = w0 * a.x + w1 * b.x;
  o.y = w0 * a.y + w1 * b.y;
  o.z = w0 * a.z + w1 * b.z;
  o.w = w0 * a.w + w1 * b.w;
  ((float4*)out)[idx] = o;
}

extern "C" void kernel_launch(void* const* d_in, const int* in_sizes, int n_in,
                              void* d_out, int out_size, void* d_ws, size_t ws_size,
                              hipStream_t stream) {
  const float* x  = (const float*)d_in[0];
  const float* gw = (const float*)d_in[1];
  const float* gb = (const float*)d_in[2];
  const float* w1 = (const float*)d_in[3];
  const float* b1 = (const float*)d_in[4];
  const float* w2 = (const float*)d_in[5];
  const float* b2 = (const float*)d_in[6];
  const float* wg = (const float*)d_in[7];
  const float* bg = (const float*)d_in[8];
  const float* w3 = (const float*)d_in[9];
  const float* b3 = (const float*)d_in[10];
  float* out = (float*)d_out;

  char* ws = (char*)d_ws;
  int* cnt      = (int*)(ws + 0);
  int* cnt2     = (int*)(ws + 64);
  int* off      = (int*)(ws + 128);
  int* topi     = (int*)(ws + 256);
  float* topw   = (float*)(ws + 256 + NT * 2 * 4);
  int* pair_tok = (int*)(ws + 256 + NT * 2 * 4 * 2);
  int* pair_pos = (int*)(ws + 256 + NT * 2 * 4 * 3);
  char* big = ws + 256 + NT * 2 * 4 * 4;
  bf16* Z = (bf16*)big;                                     // [NPAIR][DFF] bf16 = 16 MB
  bf16* S = (bf16*)(big + (size_t)NPAIR * DFF * 2);         // 16 MB
  float* Y = (float*)(big + (size_t)NPAIR * DFF * 4);       // [NPAIR][H] f32 = 16 MB

  hipMemsetAsync(d_ws, 0, 256, stream);  // cnt, cnt2, off
  gate_kernel<<<NT, 64, 0, stream>>>(x, gw, gb, cnt, topi, topw);
  prefix_kernel<<<1, 64, 0, stream>>>(cnt, off);
  scatter_kernel<<<NT / 256, 256, 0, stream>>>(topi, cnt2, off, pair_tok, pair_pos);
  ffn1_kernel<<<dim3(DFF / BN, NE, NT / BM), 256, 0, stream>>>(x, w1, b1, w2, b2, off, pair_tok, Z);
  ffn2_kernel<<<dim3(DFF / BN, NE, NT / BM), 256, 0, stream>>>(Z, wg, bg, off, S);
  ffn3_kernel<<<dim3(H / BN, NE, NT / BM), 256, 0, stream>>>(S, w3, b3, off, Y);
  combine_kernel<<<(NT * H / 4) / 256, 256, 0, stream>>>(Y, pair_pos, topw, out);
}

// Round 2
// 609.379 us; speedup vs baseline: 1.3844x; 1.3844x over previous
//
#include <hip/hip_runtime.h>

#define H 1024
#define DFF 2048
#define NE 8
#define NT 2048            // B*S tokens
#define NPAIR (NT * 2)     // TOPK=2

typedef __bf16 bf16;
typedef __bf16 bf16x8 __attribute__((ext_vector_type(8)));
typedef __bf16 bf16x4 __attribute__((ext_vector_type(4)));
typedef float f32x4 __attribute__((ext_vector_type(4)));

__device__ __forceinline__ void async_copy16(const void* g, void* l) {
  __builtin_amdgcn_global_load_lds(
      (const __attribute__((address_space(1))) unsigned int*)g,
      (__attribute__((address_space(3))) unsigned int*)l, 16, 0, 0);
}

// ---------------- gate: logits -> top2 -> softmax ----------------
__global__ __launch_bounds__(64) void gate_kernel(
    const float* __restrict__ x, const float* __restrict__ gw,
    const float* __restrict__ gb, int* __restrict__ cnt,
    int* __restrict__ topi, float* __restrict__ topw) {
  int t = blockIdx.x;
  int lane = threadIdx.x;
  const float* xr = x + (size_t)t * H;
  float acc[NE];
#pragma unroll
  for (int e = 0; e < NE; ++e) acc[e] = 0.f;
  for (int i = lane; i < H; i += 64) {
    float xv = xr[i];
    const float* g = gw + (size_t)i * NE;
#pragma unroll
    for (int e = 0; e < NE; ++e) acc[e] += xv * g[e];
  }
#pragma unroll
  for (int e = 0; e < NE; ++e) {
    for (int off = 32; off > 0; off >>= 1)
      acc[e] += __shfl_down(acc[e], off, 64);
  }
  if (lane == 0) {
    float v[NE];
#pragma unroll
    for (int e = 0; e < NE; ++e) v[e] = acc[e] + gb[e];
    int i1 = 0;
#pragma unroll
    for (int e = 1; e < NE; ++e) if (v[e] > v[i1]) i1 = e;     // lowest index on ties (jax top_k)
    int i2 = (i1 == 0) ? 1 : 0;
#pragma unroll
    for (int e = 0; e < NE; ++e) if (e != i1 && v[e] > v[i2]) i2 = e;
    float d = expf(v[i2] - v[i1]);       // <= 1
    float p1 = 1.f / (1.f + d);
    float p2 = d * p1;
    topi[2 * t] = i1; topi[2 * t + 1] = i2;
    topw[2 * t] = p1; topw[2 * t + 1] = p2;
    atomicAdd(&cnt[i1], 1);
    atomicAdd(&cnt[i2], 1);
  }
}

__global__ void prefix_kernel(const int* __restrict__ cnt, int* __restrict__ off) {
  if (threadIdx.x == 0 && blockIdx.x == 0) {
    int s = 0;
    for (int e = 0; e < NE; ++e) { off[e] = s; s += cnt[e]; }
    off[NE] = s;
  }
}

__global__ __launch_bounds__(256) void scatter_kernel(
    const int* __restrict__ topi, int* __restrict__ cnt2,
    const int* __restrict__ off, int* __restrict__ pair_tok,
    int* __restrict__ pair_pos) {
  int t = blockIdx.x * 256 + threadIdx.x;
  if (t >= NT) return;
#pragma unroll
  for (int k = 0; k < 2; ++k) {
    int e = topi[2 * t + k];
    int idx = atomicAdd(&cnt2[e], 1);
    int pos = off[e] + idx;
    pair_tok[pos] = t;
    pair_pos[2 * t + k] = pos;
  }
}

// ---------------- fp32 -> bf16 elementwise (x) ----------------
__global__ __launch_bounds__(256) void conv_x_kernel(const float* __restrict__ in,
                                                     bf16* __restrict__ out) {
  int i = (blockIdx.x * 256 + threadIdx.x) * 4;
  float4 v = *(const float4*)(in + i);
  bf16x4 o = {(bf16)v.x, (bf16)v.y, (bf16)v.z, (bf16)v.w};
  *(bf16x4*)(out + i) = o;
}

// ---------------- transpose+convert: in [E][K][N] f32 -> out [E][N][K] bf16 ----------------
#define TP 72
__global__ __launch_bounds__(256) void tconv_kernel(const float* __restrict__ in,
                                                    bf16* __restrict__ out,
                                                    int K, int N) {
  int e = blockIdx.z;
  int k0 = blockIdx.y * 64, n0 = blockIdx.x * 64;
  __shared__ bf16 T[64 * TP];
  const float* src = in + ((size_t)e * K + k0) * N + n0;
  bf16* dst = out + ((size_t)e * N + n0) * K + k0;
  int t = threadIdx.x;
  int ln = (t & 15) * 4, lk = t >> 4;
#pragma unroll
  for (int it = 0; it < 4; ++it) {
    int kk = it * 16 + lk;
    float4 v = *(const float4*)(src + (size_t)kk * N + ln);
    T[(ln + 0) * TP + kk] = (bf16)v.x;
    T[(ln + 1) * TP + kk] = (bf16)v.y;
    T[(ln + 2) * TP + kk] = (bf16)v.z;
    T[(ln + 3) * TP + kk] = (bf16)v.w;
  }
  __syncthreads();
  int sk = (t & 7) * 8, sn = t >> 3;
#pragma unroll
  for (int it = 0; it < 2; ++it) {
    int nn = it * 32 + sn;
    *(bf16x8*)(dst + (size_t)nn * K + sk) = *(const bf16x8*)&T[nn * TP + sk];
  }
}

// ---------------- stage 1: Z = (x@w1+b1)*(x@w2+b2)  [BM=128, BN=64 dual] ----------------
__global__ __launch_bounds__(256) void ffn1_kernel(
    const bf16* __restrict__ xb, const bf16* __restrict__ w1t,
    const float* __restrict__ b1, const bf16* __restrict__ w2t,
    const float* __restrict__ b2, const int* __restrict__ off,
    const int* __restrict__ pair_tok, bf16* __restrict__ Z) {
  int e = blockIdx.y;
  int base = off[e];
  int count = off[e + 1] - base;
  int m0 = blockIdx.z * 128;
  if (m0 >= count) return;
  int n0 = blockIdx.x * 64;

  __shared__ bf16 As[128 * 32];
  __shared__ bf16 B1s[64 * 32];
  __shared__ bf16 B2s[64 * 32];

  int tid = threadIdx.x;
  int wave = tid >> 6, lane = tid & 63;
  int quad = lane >> 4, l16 = lane & 15;
  int wm = wave & 1, wn = wave >> 1;

  int sr = lane >> 2, sc = lane & 3;
  int chunk = (sc ^ (sr & 3)) * 16;

  int ar0 = m0 + wave * 32 + sr;      if (ar0 >= count) ar0 = count - 1;
  int ar1 = m0 + wave * 32 + 16 + sr; if (ar1 >= count) ar1 = count - 1;
  int tok0 = pair_tok[base + ar0];
  int tok1 = pair_tok[base + ar1];
  const char* ap0 = (const char*)(xb + (size_t)tok0 * H) + chunk;
  const char* ap1 = (const char*)(xb + (size_t)tok1 * H) + chunk;

  const char* w1e = (const char*)(w1t + (size_t)e * DFF * H);
  const char* w2e = (const char*)(w2t + (size_t)e * DFF * H);
  const char* b1p = w1e + (size_t)(n0 + wave * 16 + sr) * H * 2 + chunk;
  const char* b2p = w2e + (size_t)(n0 + wave * 16 + sr) * H * 2 + chunk;

  char* asd  = (char*)As  + wave * 2048;
  char* b1sd = (char*)B1s + wave * 1024;
  char* b2sd = (char*)B2s + wave * 1024;

  int fsw = (quad ^ (l16 & 3)) * 16 + l16 * 64;
  const char* ar = (const char*)As + wm * 4096 + fsw;    // + fm*1024
  const char* b1r = (const char*)B1s + wn * 2048 + fsw;  // + fn*1024
  const char* b2r = (const char*)B2s + wn * 2048 + fsw;

  f32x4 acc1[4][2] = {};
  f32x4 acc2[4][2] = {};

  for (int k0 = 0; k0 < H * 2; k0 += 64) {
    async_copy16(ap0 + k0, asd);
    async_copy16(ap1 + k0, asd + 1024);
    async_copy16(b1p + k0, b1sd);
    async_copy16(b2p + k0, b2sd);
    __syncthreads();
    bf16x8 af[4], bf1[2], bf2[2];
#pragma unroll
    for (int i = 0; i < 4; ++i) af[i] = *(const bf16x8*)(ar + i * 1024);
#pragma unroll
    for (int i = 0; i < 2; ++i) bf1[i] = *(const bf16x8*)(b1r + i * 1024);
#pragma unroll
    for (int i = 0; i < 2; ++i) bf2[i] = *(const bf16x8*)(b2r + i * 1024);
#pragma unroll
    for (int fm = 0; fm < 4; ++fm)
#pragma unroll
      for (int fn = 0; fn < 2; ++fn) {
        acc1[fm][fn] = __builtin_amdgcn_mfma_f32_16x16x32_bf16(af[fm], bf1[fn], acc1[fm][fn], 0, 0, 0);
        acc2[fm][fn] = __builtin_amdgcn_mfma_f32_16x16x32_bf16(af[fm], bf2[fn], acc2[fm][fn], 0, 0, 0);
      }
    __syncthreads();
  }

  int mb = m0 + wm * 64;
#pragma unroll
  for (int fm = 0; fm < 4; ++fm) {
#pragma unroll
    for (int fn = 0; fn < 2; ++fn) {
      int n = n0 + wn * 32 + fn * 16 + l16;
      float bb1 = b1[e * DFF + n];
      float bb2 = b2[e * DFF + n];
#pragma unroll
      for (int r = 0; r < 4; ++r) {
        int m = mb + fm * 16 + quad * 4 + r;
        if (m < count) {
          float zv = (acc1[fm][fn][r] + bb1) * (acc2[fm][fn][r] + bb2);
          Z[(size_t)(base + m) * DFF + n] = (bf16)zv;
        }
      }
    }
  }
}

// ---------------- stage 2: S = silu(Z@wg + bg)  [BM=128, BN=128] ----------------
__global__ __launch_bounds__(256) void ffn2_kernel(
    const bf16* __restrict__ Z, const bf16* __restrict__ wgt,
    const float* __restrict__ bg, const int* __restrict__ off,
    bf16* __restrict__ S) {
  int e = blockIdx.y;
  int base = off[e];
  int count = off[e + 1] - base;
  int m0 = blockIdx.z * 128;
  if (m0 >= count) return;
  int n0 = blockIdx.x * 128;

  __shared__ bf16 As[128 * 32];
  __shared__ bf16 Bs[128 * 32];

  int tid = threadIdx.x;
  int wave = tid >> 6, lane = tid & 63;
  int quad = lane >> 4, l16 = lane & 15;
  int wm = wave & 1, wn = wave >> 1;

  int sr = lane >> 2, sc = lane & 3;
  int chunk = (sc ^ (sr & 3)) * 16;

  int ar0 = m0 + wave * 32 + sr;      if (ar0 >= count) ar0 = count - 1;
  int ar1 = m0 + wave * 32 + 16 + sr; if (ar1 >= count) ar1 = count - 1;
  const char* ap0 = (const char*)(Z + (size_t)(base + ar0) * DFF) + chunk;
  const char* ap1 = (const char*)(Z + (size_t)(base + ar1) * DFF) + chunk;

  const char* we = (const char*)(wgt + (size_t)e * DFF * DFF);
  const char* bp0 = we + (size_t)(n0 + wave * 32 + sr) * DFF * 2 + chunk;
  const char* bp1 = we + (size_t)(n0 + wave * 32 + 16 + sr) * DFF * 2 + chunk;

  char* asd = (char*)As + wave * 2048;
  char* bsd = (char*)Bs + wave * 2048;

  int fsw = (quad ^ (l16 & 3)) * 16 + l16 * 64;
  const char* ar = (const char*)As + wm * 4096 + fsw;
  const char* br = (const char*)Bs + wn * 4096 + fsw;

  f32x4 acc[4][4] = {};

  for (int k0 = 0; k0 < DFF * 2; k0 += 64) {
    async_copy16(ap0 + k0, asd);
    async_copy16(ap1 + k0, asd + 1024);
    async_copy16(bp0 + k0, bsd);
    async_copy16(bp1 + k0, bsd + 1024);
    __syncthreads();
    bf16x8 af[4], bfr[4];
#pragma unroll
    for (int i = 0; i < 4; ++i) af[i] = *(const bf16x8*)(ar + i * 1024);
#pragma unroll
    for (int i = 0; i < 4; ++i) bfr[i] = *(const bf16x8*)(br + i * 1024);
#pragma unroll
    for (int fm = 0; fm < 4; ++fm)
#pragma unroll
      for (int fn = 0; fn < 4; ++fn)
        acc[fm][fn] = __builtin_amdgcn_mfma_f32_16x16x32_bf16(af[fm], bfr[fn], acc[fm][fn], 0, 0, 0);
    __syncthreads();
  }

  int mb = m0 + wm * 64;
#pragma unroll
  for (int fm = 0; fm < 4; ++fm) {
#pragma unroll
    for (int fn = 0; fn < 4; ++fn) {
      int n = n0 + wn * 64 + fn * 16 + l16;
      float bb = bg[e * DFF + n];
#pragma unroll
      for (int r = 0; r < 4; ++r) {
        int m = mb + fm * 16 + quad * 4 + r;
        if (m < count) {
          float v = acc[fm][fn][r] + bb;
          S[(size_t)(base + m) * DFF + n] = (bf16)(v / (1.f + __expf(-v)));
        }
      }
    }
  }
}

// ---------------- stage 3: Y = S@w3 + b3  [BM=128, BN=64] ----------------
__global__ __launch_bounds__(256) void ffn3_kernel(
    const bf16* __restrict__ S, const bf16* __restrict__ w3t,
    const float* __restrict__ b3, const int* __restrict__ off,
    bf16* __restrict__ Y) {
  int e = blockIdx.y;
  int base = off[e];
  int count = off[e + 1] - base;
  int m0 = blockIdx.z * 128;
  if (m0 >= count) return;
  int n0 = blockIdx.x * 64;

  __shared__ bf16 As[128 * 32];
  __shared__ bf16 Bs[64 * 32];

  int tid = threadIdx.x;
  int wave = tid >> 6, lane = tid & 63;
  int quad = lane >> 4, l16 = lane & 15;
  int wm = wave & 1, wn = wave >> 1;

  int sr = lane >> 2, sc = lane & 3;
  int chunk = (sc ^ (sr & 3)) * 16;

  int ar0 = m0 + wave * 32 + sr;      if (ar0 >= count) ar0 = count - 1;
  int ar1 = m0 + wave * 32 + 16 + sr; if (ar1 >= count) ar1 = count - 1;
  const char* ap0 = (const char*)(S + (size_t)(base + ar0) * DFF) + chunk;
  const char* ap1 = (const char*)(S + (size_t)(base + ar1) * DFF) + chunk;

  const char* we = (const char*)(w3t + (size_t)e * H * DFF);
  const char* bp0 = we + (size_t)(n0 + wave * 16 + sr) * DFF * 2 + chunk;

  char* asd = (char*)As + wave * 2048;
  char* bsd = (char*)Bs + wave * 1024;

  int fsw = (quad ^ (l16 & 3)) * 16 + l16 * 64;
  const char* ar = (const char*)As + wm * 4096 + fsw;
  const char* br = (const char*)Bs + wn * 2048 + fsw;

  f32x4 acc[4][2] = {};

  for (int k0 = 0; k0 < DFF * 2; k0 += 64) {
    async_copy16(ap0 + k0, asd);
    async_copy16(ap1 + k0, asd + 1024);
    async_copy16(bp0 + k0, bsd);
    __syncthreads();
    bf16x8 af[4], bfr[2];
#pragma unroll
    for (int i = 0; i < 4; ++i) af[i] = *(const bf16x8*)(ar + i * 1024);
#pragma unroll
    for (int i = 0; i < 2; ++i) bfr[i] = *(const bf16x8*)(br + i * 1024);
#pragma unroll
    for (int fm = 0; fm < 4; ++fm)
#pragma unroll
      for (int fn = 0; fn < 2; ++fn)
        acc[fm][fn] = __builtin_amdgcn_mfma_f32_16x16x32_bf16(af[fm], bfr[fn], acc[fm][fn], 0, 0, 0);
    __syncthreads();
  }

  int mb = m0 + wm * 64;
#pragma unroll
  for (int fm = 0; fm < 4; ++fm) {
#pragma unroll
    for (int fn = 0; fn < 2; ++fn) {
      int n = n0 + wn * 32 + fn * 16 + l16;
      float bb = b3[e * H + n];
#pragma unroll
      for (int r = 0; r < 4; ++r) {
        int m = mb + fm * 16 + quad * 4 + r;
        if (m < count) {
          Y[(size_t)(base + m) * H + n] = (bf16)(acc[fm][fn][r] + bb);
        }
      }
    }
  }
}

// ---------------- combine: out[t] = w0*Y[p0] + w1*Y[p1] ----------------
__global__ __launch_bounds__(256) void combine_kernel(
    const bf16* __restrict__ Y, const int* __restrict__ pair_pos,
    const float* __restrict__ topw, float* __restrict__ out) {
  int idx = blockIdx.x * 256 + threadIdx.x;   // one float4 per thread
  int t = idx >> 8;                           // H/4 = 256 float4 per token
  int h4 = idx & 255;
  int p0 = pair_pos[2 * t], p1 = pair_pos[2 * t + 1];
  float w0 = topw[2 * t], w1 = topw[2 * t + 1];
  bf16x4 a = *(const bf16x4*)(Y + (size_t)p0 * H + h4 * 4);
  bf16x4 b = *(const bf16x4*)(Y + (size_t)p1 * H + h4 * 4);
  float4 o;
  o.x = w0 * (float)a[0] + w1 * (float)b[0];
  o.y = w0 * (float)a[1] + w1 * (float)b[1];
  o.z = w0 * (float)a[2] + w1 * (float)b[2];
  o.w = w0 * (float)a[3] + w1 * (float)b[3];
  ((float4*)out)[idx] = o;
}

extern "C" void kernel_launch(void* const* d_in, const int* in_sizes, int n_in,
                              void* d_out, int out_size, void* d_ws, size_t ws_size,
                              hipStream_t stream) {
  const float* x  = (const float*)d_in[0];
  const float* gw = (const float*)d_in[1];
  const float* gb = (const float*)d_in[2];
  const float* w1 = (const float*)d_in[3];
  const float* b1 = (const float*)d_in[4];
  const float* w2 = (const float*)d_in[5];
  const float* b2 = (const float*)d_in[6];
  const float* wg = (const float*)d_in[7];
  const float* bg = (const float*)d_in[8];
  const float* w3 = (const float*)d_in[9];
  const float* b3 = (const float*)d_in[10];
  float* out = (float*)d_out;

  char* ws = (char*)d_ws;
  int* cnt      = (int*)(ws + 0);
  int* cnt2     = (int*)(ws + 64);
  int* off      = (int*)(ws + 128);
  int* topi     = (int*)(ws + 4096);
  float* topw   = (float*)(ws + 4096 + 16384);
  int* pair_tok = (int*)(ws + 4096 + 16384 * 2);
  int* pair_pos = (int*)(ws + 4096 + 16384 * 3);

  const size_t MB = 1024 * 1024;
  char* big = ws + MB;
  bf16* xb  = (bf16*)(big);                 // 4 MB   [NT][H]
  bf16* w1t = (bf16*)(big + 4   * MB);      // 32 MB  [E][DFF][H]
  bf16* w2t = (bf16*)(big + 36  * MB);      // 32 MB  [E][DFF][H]
  bf16* wgt = (bf16*)(big + 68  * MB);      // 64 MB  [E][DFF][DFF]
  bf16* w3t = (bf16*)(big + 132 * MB);      // 32 MB  [E][H][DFF]
  bf16* Z   = (bf16*)(big + 164 * MB);      // 16 MB  [NPAIR][DFF]
  bf16* S   = (bf16*)(big + 180 * MB);      // 16 MB  [NPAIR][DFF]
  bf16* Y   = (bf16*)(big + 196 * MB);      // 8 MB   [NPAIR][H]

  hipMemsetAsync(d_ws, 0, 256, stream);  // cnt, cnt2, off
  gate_kernel<<<NT, 64, 0, stream>>>(x, gw, gb, cnt, topi, topw);
  prefix_kernel<<<1, 64, 0, stream>>>(cnt, off);
  scatter_kernel<<<NT / 256, 256, 0, stream>>>(topi, cnt2, off, pair_tok, pair_pos);

  conv_x_kernel<<<NT * H / 1024, 256, 0, stream>>>(x, xb);
  tconv_kernel<<<dim3(DFF / 64, H / 64,  NE), 256, 0, stream>>>(w1, w1t, H,  DFF);
  tconv_kernel<<<dim3(DFF / 64, H / 64,  NE), 256, 0, stream>>>(w2, w2t, H,  DFF);
  tconv_kernel<<<dim3(DFF / 64, DFF / 64, NE), 256, 0, stream>>>(wg, wgt, DFF, DFF);
  tconv_kernel<<<dim3(H / 64,  DFF / 64, NE), 256, 0, stream>>>(w3, w3t, DFF, H);

  ffn1_kernel<<<dim3(DFF / 64, NE, NPAIR / 128), 256, 0, stream>>>(xb, w1t, b1, w2t, b2, off, pair_tok, Z);
  ffn2_kernel<<<dim3(DFF / 128, NE, NPAIR / 128), 256, 0, stream>>>(Z, wgt, bg, off, S);
  ffn3_kernel<<<dim3(H / 64, NE, NPAIR / 128), 256, 0, stream>>>(S, w3t, b3, off, Y);
  combine_kernel<<<(NT * H / 4) / 256, 256, 0, stream>>>(Y, pair_pos, topw, out);
}